// Round 7
// baseline (2079.499 us; speedup 1.0000x reference)
//
#include <hip/hip_runtime.h>
#include <hip/hip_bf16.h>

// ============================================================================
// PPO agent fused forward (round 7):
//  r6 landed latency-bound: 2 waves/SIMD (LDS-capped), 11M bank conflicts,
//  A-fragment re-read from LDS 8x per layer in the inner loop.
//  This round:
//   - A-frags in REGISTERS (loaded once per layer, 32 VGPRs) -> inner loop is
//     pure {global b-load -> MFMA}; LDS reads cut 8x.
//   - X tile in registers straight from global (k-permuted pack in-reg),
//     shared by actor-L1 and critic-L1. X never touches LDS.
//   - single 8KB LDS buffer/wave (in-place LN safe now) -> 16KB/block ->
//     10 blocks/CU = 20 waves/CU (62% occupancy cap, was 23%).
//   - no __syncthreads (waves independent); sched_barrier(0) at layer edges.
//  Numerics identical to r6: absmax ~0.125.
// ============================================================================

#define T_SZ 524288
#define GL 0.9405f   // GAMMA*LAM

typedef __attribute__((ext_vector_type(8))) short bf16x8;   // 8 bf16 (4 VGPRs)
typedef __attribute__((ext_vector_type(4))) float f32x4;

// ws layout (bf16 elements); weights stored [N][K], k-permuted
#define OFF_AW1T 0        // [256][64]
#define OFF_AW2T 16384    // [256][256]
#define OFF_AW3T 81920    // [32][256]  rows >=18 zero
#define OFF_CW1T 90112    // [256][64]
#define OFF_CW2T 106496   // [256][256]
#define OFF_CW3T 172032   // [16][256]  rows >=1 zero
#define W_ELEMS  176128
#define OFF_DELTAS_BYTES 352256

// k = p*32 + h*16 + w (w=k&15, h=(k>>4)&1) -> pos = p*32 + w*2 + h
// Applied to BOTH A (activations) and B (weights) -> MFMA k-sum invariant.
__device__ __forceinline__ int perm_k(int k) {
  return (k & ~31) | ((k & 15) << 1) | ((k >> 4) & 1);
}

// 16B-granular XOR swizzle
__device__ __forceinline__ void* lds_at(void* base, int row, int colByte, int strideB) {
  return (char*)base + row * strideB + (colByte ^ ((row & 7) << 4));
}

__device__ __forceinline__ unsigned pack2(float a, float b) {
  union { __hip_bfloat16 h; unsigned short u; } ua, ub;
  ua.h = __float2bfloat16(a); ub.h = __float2bfloat16(b);
  return (unsigned)ua.u | ((unsigned)ub.u << 16);
}

__device__ __forceinline__ void unpack2(unsigned u, float& a, float& b) {
  union { unsigned u; float f; } x, y;
  x.u = u << 16; y.u = u & 0xFFFF0000u;
  a = x.f; b = y.f;
}

// ---------------------------------------------------------------------------
// X tile (16 rows x 64 fp32) -> 2 k-permuted bf16x8 frags per lane, no LDS.
// Lane (q,c): row c; frag ks covers perm positions ks*32 + q*8 + [0,8):
//   element j pairs k = ks*32 + 4q + (j>>1) with +16 (h bit alternates).
__device__ __forceinline__ void load_x_frags(const float* __restrict__ src,
                                             int c, int q, bf16x8* xf) {
  const float* rp = src + (size_t)c * 64;
#pragma unroll
  for (int ks = 0; ks < 2; ++ks) {
    float4 a = *(const float4*)(rp + ks * 32 + 4 * q);
    float4 b = *(const float4*)(rp + ks * 32 + 4 * q + 16);
    unsigned u[4];
    u[0] = pack2(a.x, b.x); u[1] = pack2(a.y, b.y);
    u[2] = pack2(a.z, b.z); u[3] = pack2(a.w, b.w);
    xf[ks] = *(bf16x8*)u;
  }
}

// ---------------------------------------------------------------------------
// Linear(K->256) + bias + LayerNorm + ReLU.
// A-frags in regs (af[K/32]); B streamed from global [N][K] k-permuted bf16.
// Pass 1: per column-pair MFMA -> bias -> s/ss -> pre-LN bf16 pair to ACT.
// Reduce; pass 2 RMW normalize+ReLU; then load next layer's frags into of[8].
// ACT in-place safe: af already in registers.
template<int K>
__device__ __forceinline__ void layer_ln(const bf16x8* af,
    const __hip_bfloat16* __restrict__ Wt,
    const float* __restrict__ bias, const float* __restrict__ gam,
    const float* __restrict__ bet, void* ACT, int c, int q, bf16x8* of) {
  float s[4] = {0, 0, 0, 0}, ss[4] = {0, 0, 0, 0};
#pragma unroll
  for (int p = 0; p < 8; ++p) {
    f32x4 acc0 = {0.f, 0.f, 0.f, 0.f}, acc1 = {0.f, 0.f, 0.f, 0.f};
    const __hip_bfloat16* wp = Wt + (size_t)(32 * p + c) * K + q * 8;
#pragma unroll
    for (int ks = 0; ks < K / 32; ++ks) {
      bf16x8 b0 = *(const bf16x8*)(wp + ks * 32);
      bf16x8 b1 = *(const bf16x8*)(wp + (size_t)16 * K + ks * 32);
      acc0 = __builtin_amdgcn_mfma_f32_16x16x32_bf16(af[ks], b0, acc0, 0, 0, 0);
      acc1 = __builtin_amdgcn_mfma_f32_16x16x32_bf16(af[ks], b1, acc1, 0, 0, 0);
    }
    const float bb0 = bias[32 * p + c], bb1 = bias[32 * p + 16 + c];
#pragma unroll
    for (int r = 0; r < 4; ++r) {
      float v0 = acc0[r] + bb0, v1 = acc1[r] + bb1;
      s[r] += v0 + v1;
      ss[r] += v0 * v0 + v1 * v1;
      *(unsigned*)lds_at(ACT, q * 4 + r, p * 64 + c * 4, 512) = pack2(v0, v1);
    }
  }
  // row stats over the 16 c-lanes (lane = q*16+c; xor m<16 flips c only)
#pragma unroll
  for (int m = 1; m < 16; m <<= 1) {
#pragma unroll
    for (int r = 0; r < 4; ++r) {
      s[r]  += __shfl_xor(s[r],  m, 64);
      ss[r] += __shfl_xor(ss[r], m, 64);
    }
  }
  float mean[4], rs[4];
#pragma unroll
  for (int r = 0; r < 4; ++r) {
    mean[r] = s[r] * (1.f / 256.f);
    float var = ss[r] * (1.f / 256.f) - mean[r] * mean[r];
    rs[r] = rsqrtf(var + 1e-5f);
  }
  // pass 2: RMW normalize + ReLU (per-lane own slots)
#pragma unroll
  for (int p = 0; p < 8; ++p) {
    const float g0 = gam[32 * p + c],      b0 = bet[32 * p + c];
    const float g1 = gam[32 * p + 16 + c], b1 = bet[32 * p + 16 + c];
#pragma unroll
    for (int r = 0; r < 4; ++r) {
      unsigned* ap = (unsigned*)lds_at(ACT, q * 4 + r, p * 64 + c * 4, 512);
      float v0, v1;
      unpack2(*ap, v0, v1);
      float w0 = fmaxf((v0 - mean[r]) * rs[r] * g0 + b0, 0.f);
      float w1 = fmaxf((v1 - mean[r]) * rs[r] * g1 + b1, 0.f);
      *ap = pack2(w0, w1);
    }
  }
  // next layer's A-frags into registers (cross-lane; per-wave LDS is in-order)
#pragma unroll
  for (int ks = 0; ks < 8; ++ks)
    of[ks] = *(const bf16x8*)lds_at(ACT, c, ks * 64 + q * 16, 512);
}

// small final GEMM (no LN): NT column-tiles of 16, K=256, A-frags in regs
template<int NT>
__device__ __forceinline__ void run_small(const bf16x8* af,
    const __hip_bfloat16* __restrict__ Wt, int c, int q, f32x4* acc) {
#pragma unroll
  for (int nt = 0; nt < NT; ++nt) acc[nt] = (f32x4){0.f, 0.f, 0.f, 0.f};
#pragma unroll
  for (int ks = 0; ks < 8; ++ks) {
#pragma unroll
    for (int nt = 0; nt < NT; ++nt) {
      bf16x8 b = *(const bf16x8*)(Wt + (size_t)(nt * 16 + c) * 256 + ks * 32 + q * 8);
      acc[nt] = __builtin_amdgcn_mfma_f32_16x16x32_bf16(af[ks], b, acc[nt], 0, 0, 0);
    }
  }
}

__device__ __forceinline__ void softmax_write(f32x4* acc3,
    const float* __restrict__ ab3, float* __restrict__ out,
    int grow0, int c, int q) {
  float b0 = ab3[c];
  float b1 = (c < 2) ? ab3[16 + c] : 0.f;
#pragma unroll
  for (int r = 0; r < 4; ++r) {
    float x0 = acc3[0][r] + b0;
    float x1 = (c < 2) ? (acc3[1][r] + b1) : -1e30f;
    float mx = fmaxf(x0, x1);
#pragma unroll
    for (int m = 1; m < 16; m <<= 1) mx = fmaxf(mx, __shfl_xor(mx, m, 64));
    float e0 = __expf(x0 - mx);
    float e1 = (c < 2) ? __expf(x1 - mx) : 0.f;
    float sm = e0 + e1;
#pragma unroll
    for (int m = 1; m < 16; m <<= 1) sm += __shfl_xor(sm, m, 64);
    float inv = 1.f / sm;
    int gr = grow0 + q * 4 + r;
    out[(size_t)gr * 20 + c] = e0 * inv;
    if (c < 2) out[(size_t)gr * 20 + 16 + c] = e1 * inv;
  }
}

// ---------------------------------------------------------------------------
__global__ void prep_weights(const float* __restrict__ aw1, const float* __restrict__ aw2,
                             const float* __restrict__ aw3, const float* __restrict__ cw1,
                             const float* __restrict__ cw2, const float* __restrict__ cw3,
                             __hip_bfloat16* __restrict__ wb) {
  int i = blockIdx.x * 256 + threadIdx.x;
  if (i >= W_ELEMS) return;
  float v; int dst;
  if (i < OFF_AW2T)      { int j = i;            int n = j >> 6, k = j & 63;  v = aw1[k * 256 + n];              dst = OFF_AW1T + n * 64  + perm_k(k); }
  else if (i < OFF_AW3T) { int j = i - OFF_AW2T; int n = j >> 8, k = j & 255; v = aw2[k * 256 + n];              dst = OFF_AW2T + n * 256 + perm_k(k); }
  else if (i < OFF_CW1T) { int j = i - OFF_AW3T; int n = j >> 8, k = j & 255; v = (n < 18) ? aw3[k * 18 + n] : 0.f; dst = OFF_AW3T + n * 256 + perm_k(k); }
  else if (i < OFF_CW2T) { int j = i - OFF_CW1T; int n = j >> 6, k = j & 63;  v = cw1[k * 256 + n];              dst = OFF_CW1T + n * 64  + perm_k(k); }
  else if (i < OFF_CW3T) { int j = i - OFF_CW2T; int n = j >> 8, k = j & 255; v = cw2[k * 256 + n];              dst = OFF_CW2T + n * 256 + perm_k(k); }
  else                   { int j = i - OFF_CW3T; int n = j >> 8, k = j & 255; v = (n == 0) ? cw3[k] : 0.f;       dst = OFF_CW3T + n * 256 + perm_k(k); }
  wb[dst] = __float2bfloat16(v);
}

// ---------------------------------------------------------------------------
__global__ __launch_bounds__(128, 2) void mlp_kernel(
    const float* __restrict__ states, const float* __restrict__ next_states,
    const float* __restrict__ rewards, const float* __restrict__ masks,
    const float* __restrict__ ab1, const float* __restrict__ ag1, const float* __restrict__ an1,
    const float* __restrict__ ab2, const float* __restrict__ ag2, const float* __restrict__ an2,
    const float* __restrict__ ab3,
    const float* __restrict__ cb1, const float* __restrict__ cg1, const float* __restrict__ cn1,
    const float* __restrict__ cb2, const float* __restrict__ cg2, const float* __restrict__ cn2,
    const float* __restrict__ cb3,
    const __hip_bfloat16* __restrict__ wbuf,
    float* __restrict__ deltas, float* __restrict__ out) {
  __shared__ char smem[2][8192];   // one 8KB activation buffer per wave
  const int tid = threadIdx.x;
  const int wave = tid >> 6, lane = tid & 63;
  const int c = lane & 15, q = lane >> 4;
  void* ACT = (void*)smem[wave];
  const int base = blockIdx.x * 32 + wave * 16;   // 16 timesteps per wave

  bf16x8 xf[2], af[8];

  // ---- X(states) -> regs, shared by actor-L1 and critic-L1 ----
  load_x_frags(states + (size_t)base * 64, c, q, xf);

  // ---- ACTOR(states) ----
  layer_ln<64>(xf, wbuf + OFF_AW1T, ab1, ag1, an1, ACT, c, q, af);
  __builtin_amdgcn_sched_barrier(0);
  layer_ln<256>(af, wbuf + OFF_AW2T, ab2, ag2, an2, ACT, c, q, af);
  __builtin_amdgcn_sched_barrier(0);
  {
    f32x4 p3[2];
    run_small<2>(af, wbuf + OFF_AW3T, c, q, p3);
    softmax_write(p3, ab3, out, base, c, q);
  }
  __builtin_amdgcn_sched_barrier(0);

  // ---- CRITIC(states) ---- (xf still in regs)
  layer_ln<64>(xf, wbuf + OFF_CW1T, cb1, cg1, cn1, ACT, c, q, af);
  __builtin_amdgcn_sched_barrier(0);
  layer_ln<256>(af, wbuf + OFF_CW2T, cb2, cg2, cn2, ACT, c, q, af);
  __builtin_amdgcn_sched_barrier(0);
  float vst[4];
  {
    f32x4 v[1];
    run_small<1>(af, wbuf + OFF_CW3T, c, q, v);
    const float b3 = cb3[0];
#pragma unroll
    for (int r = 0; r < 4; ++r) vst[r] = v[0][r] + b3;
  }
  __builtin_amdgcn_sched_barrier(0);

  // ---- CRITIC(next_states) ----
  load_x_frags(next_states + (size_t)base * 64, c, q, xf);
  layer_ln<64>(xf, wbuf + OFF_CW1T, cb1, cg1, cn1, ACT, c, q, af);
  __builtin_amdgcn_sched_barrier(0);
  layer_ln<256>(af, wbuf + OFF_CW2T, cb2, cg2, cn2, ACT, c, q, af);
  __builtin_amdgcn_sched_barrier(0);
  {
    f32x4 v[1];
    run_small<1>(af, wbuf + OFF_CW3T, c, q, v);
    const float b3 = cb3[0];
    if (c == 0) {
#pragma unroll
      for (int r = 0; r < 4; ++r) {
        const int gr = base + q * 4 + r;
        const float nv = v[0][r] + b3;
        out[(size_t)gr * 20 + 19] = vst[r];   // stash value; gae -> return
        deltas[gr] = rewards[gr] + 0.99f * nv * masks[gr] - vst[r];
      }
    }
  }
}

// ---------------------------------------------------------------------------
// GAE, wave-parallel: each wave owns a 512-elem chunk + 512-elem lookahead.
// Per lane: 16 contiguous elems -> local affine (A,P); log-step shfl_down
// suffix composition; exclusive carry; local rescan + RMW out.
// Truncation: GL^512 ~ 2e-14.
__global__ __launch_bounds__(256) void gae_kernel(
    const float* __restrict__ deltas, const float* __restrict__ masks,
    float* __restrict__ out) {
  const int w = (blockIdx.x * blockDim.x + threadIdx.x) >> 6;  // 0..1023
  const int lane = threadIdx.x & 63;
  const int base = w * 512;
  const int idx0 = base + lane * 16;

  float d[16], cf[16];
  if (idx0 < T_SZ) {
#pragma unroll
    for (int i = 0; i < 4; ++i) {
      *(float4*)(d + i * 4)  = *(const float4*)(deltas + idx0 + i * 4);
      *(float4*)(cf + i * 4) = *(const float4*)(masks + idx0 + i * 4);
    }
#pragma unroll
    for (int i = 0; i < 16; ++i) cf[i] *= GL;
  } else {
#pragma unroll
    for (int i = 0; i < 16; ++i) { d[i] = 0.f; cf[i] = 0.f; }
  }

  // local affine: applying this block to incoming g gives A + P*g
  float A = 0.f, P = 1.f;
#pragma unroll
  for (int i = 15; i >= 0; --i) { A = d[i] + cf[i] * A; P *= cf[i]; }

  // suffix-inclusive scan over lanes (Hillis-Steele, compose rightward)
  float As = A, Ps = P;
#pragma unroll
  for (int st = 1; st < 64; st <<= 1) {
    float An = __shfl_down(As, st, 64);
    float Pn = __shfl_down(Ps, st, 64);
    if (lane + st < 64) { As = As + Ps * An; Ps = Ps * Pn; }
  }
  float G = __shfl_down(As, 1, 64);   // exclusive: lanes l+1..63
  if (lane == 63) G = 0.f;

  if (lane < 32) {                    // first 512 elems are this wave's output
    float g = G;
#pragma unroll
    for (int i = 15; i >= 0; --i) {
      g = d[i] + cf[i] * g;
      const size_t j = (size_t)(idx0 + i);
      float val = out[j * 20 + 19];
      out[j * 20 + 18] = g;
      out[j * 20 + 19] = g + val;
    }
  }
}

// ---------------------------------------------------------------------------
extern "C" void kernel_launch(void* const* d_in, const int* in_sizes, int n_in,
                              void* d_out, int out_size, void* d_ws, size_t ws_size,
                              hipStream_t stream) {
  const float* states      = (const float*)d_in[0];
  const float* next_states = (const float*)d_in[1];
  const float* rewards     = (const float*)d_in[2];
  const float* masks       = (const float*)d_in[3];
  const float* aw1 = (const float*)d_in[4];
  const float* ab1 = (const float*)d_in[5];
  const float* ag1 = (const float*)d_in[6];
  const float* an1 = (const float*)d_in[7];
  const float* aw2 = (const float*)d_in[8];
  const float* ab2 = (const float*)d_in[9];
  const float* ag2 = (const float*)d_in[10];
  const float* an2 = (const float*)d_in[11];
  const float* aw3 = (const float*)d_in[12];
  const float* ab3 = (const float*)d_in[13];
  const float* cw1 = (const float*)d_in[14];
  const float* cb1 = (const float*)d_in[15];
  const float* cg1 = (const float*)d_in[16];
  const float* cn1 = (const float*)d_in[17];
  const float* cw2 = (const float*)d_in[18];
  const float* cb2 = (const float*)d_in[19];
  const float* cg2 = (const float*)d_in[20];
  const float* cn2 = (const float*)d_in[21];
  const float* cw3 = (const float*)d_in[22];
  const float* cb3 = (const float*)d_in[23];

  __hip_bfloat16* wbuf = (__hip_bfloat16*)d_ws;
  float* deltas = (float*)((char*)d_ws + OFF_DELTAS_BYTES);
  float* out = (float*)d_out;

  prep_weights<<<(W_ELEMS + 255) / 256, 256, 0, stream>>>(aw1, aw2, aw3, cw1, cw2, cw3, wbuf);
  mlp_kernel<<<T_SZ / 32, 128, 0, stream>>>(
      states, next_states, rewards, masks,
      ab1, ag1, an1, ab2, ag2, an2, ab3,
      cb1, cg1, cn1, cb2, cg2, cn2, cb3,
      wbuf, deltas, out);
  gae_kernel<<<256, 256, 0, stream>>>(deltas, masks, out);
}